// Round 1
// baseline (588.727 us; speedup 1.0000x reference)
//
#include <hip/hip_runtime.h>

#define MULV 32
#define BASE 9
#define ROW 288      // MULV*BASE
#define NPATH 11
#define W3J_SZ 729   // 9*9*9
#define TEDGE 2      // edges per thread in main kernel
#define UPB 4        // u values per block (one per wave)

// Path table: (i1,i2,io) blocks for IRREPS [(0,e),(1,o),(2,e)], dims {1,3,5}, offs {0,1,4}
// Order follows the reference loop (io outer, i1, i2) but order is irrelevant:
// blocks are disjoint cells of the 9x9x9 cube; values read from input w3j at runtime.
__device__ constexpr int p_o1[NPATH] = {0,1,4, 0,1,1,4, 0,1,4,4};
__device__ constexpr int p_d1[NPATH] = {1,3,5, 1,3,3,5, 1,3,5,5};
__device__ constexpr int p_o2[NPATH] = {0,1,4, 1,0,4,1, 4,1,0,4};
__device__ constexpr int p_d2[NPATH] = {1,3,5, 3,1,5,3, 5,3,1,5};
__device__ constexpr int p_o3[NPATH] = {0,0,0, 1,1,1,1, 4,4,4,4};
__device__ constexpr int p_d3[NPATH] = {1,1,1, 3,3,3,3, 5,5,5,5};

__global__ void zero_ws_kernel(float* __restrict__ ws, const int* __restrict__ dN) {
    long total = (long)dN[0] * ROW;
    long stride = (long)gridDim.x * blockDim.x;
    for (long i = (long)blockIdx.x * blockDim.x + threadIdx.x; i < total; i += stride)
        ws[i] = 0.0f;
}

__global__ void scatter_add_kernel(const float* __restrict__ x2,
                                   const int* __restrict__ idxs,
                                   float* __restrict__ x2s, int E) {
    long t = (long)blockIdx.x * blockDim.x + threadIdx.x;
    long total = (long)E * ROW;
    if (t >= total) return;
    int e = (int)(t / ROW);
    int c = (int)(t - (long)e * ROW);
    atomicAdd(&x2s[(long)idxs[e] * ROW + c], x2[t]);
}

__global__ __launch_bounds__(256) void contract_kernel(
    const float* __restrict__ x1, const int* __restrict__ idxs,
    const float* __restrict__ x2s, const float* __restrict__ weights,
    const float* __restrict__ w3j, float* __restrict__ out, int E)
{
    __shared__ float lds_ww[UPB * W3J_SZ];
    const int tid = threadIdx.x;
    const int u0  = blockIdx.y * UPB;

    // Build combined ww3j[u, i,j,k] = sum_p weights[u,p] * w3j[p,i,j,k] for this block's 4 u's.
    for (int t = tid; t < UPB * W3J_SZ; t += 256) {
        int ul = t / W3J_SZ;
        int r  = t - ul * W3J_SZ;
        float s = 0.0f;
        #pragma unroll
        for (int p = 0; p < NPATH; ++p)
            s += weights[(u0 + ul) * NPATH + p] * w3j[p * W3J_SZ + r];
        lds_ww[t] = s;
    }
    __syncthreads();

    const int wv   = tid >> 6;    // wave id 0..3 -> local u
    const int lane = tid & 63;
    const int u    = u0 + wv;
    const float* __restrict__ ww = &lds_ww[wv * W3J_SZ];

    const long e0 = (long)blockIdx.x * (64 * TEDGE);

    float x1v[TEDGE][BASE], x2v[TEDGE][BASE], acc[TEDGE][BASE];
    long eArr[TEDGE];
    bool vld[TEDGE];

    #pragma unroll
    for (int t = 0; t < TEDGE; ++t) {
        long e = e0 + (long)t * 64 + lane;
        eArr[t] = e;
        vld[t] = (e < (long)E);
        long esafe = vld[t] ? e : 0;
        const float* p1 = &x1[esafe * ROW + u * BASE];
        int n = idxs[esafe];
        const float* p2 = &x2s[(long)n * ROW + u * BASE];
        #pragma unroll
        for (int i = 0; i < BASE; ++i) {
            x1v[t][i] = vld[t] ? p1[i] : 0.0f;
            x2v[t][i] = vld[t] ? p2[i] : 0.0f;
            acc[t][i] = 0.0f;
        }
    }

    #pragma unroll
    for (int p = 0; p < NPATH; ++p) {
        #pragma unroll
        for (int i = 0; i < p_d1[p]; ++i) {
            #pragma unroll
            for (int j = 0; j < p_d2[p]; ++j) {
                float xx[TEDGE];
                #pragma unroll
                for (int t = 0; t < TEDGE; ++t)
                    xx[t] = x1v[t][p_o1[p] + i] * x2v[t][p_o2[p] + j];
                #pragma unroll
                for (int k = 0; k < p_d3[p]; ++k) {
                    float w = ww[(p_o1[p] + i) * 81 + (p_o2[p] + j) * 9 + (p_o3[p] + k)];
                    #pragma unroll
                    for (int t = 0; t < TEDGE; ++t)
                        acc[t][p_o3[p] + k] += w * xx[t];
                }
            }
        }
    }

    #pragma unroll
    for (int t = 0; t < TEDGE; ++t) {
        if (vld[t]) {
            float* po = &out[eArr[t] * ROW + u * BASE];
            #pragma unroll
            for (int k = 0; k < BASE; ++k) po[k] = acc[t][k];
        }
    }
}

extern "C" void kernel_launch(void* const* d_in, const int* in_sizes, int n_in,
                              void* d_out, int out_size, void* d_ws, size_t ws_size,
                              hipStream_t stream) {
    const float* x1      = (const float*)d_in[0];
    const float* x2      = (const float*)d_in[1];
    const int*   idxs    = (const int*)d_in[2];
    const float* weights = (const float*)d_in[3];
    const float* w3j     = (const float*)d_in[4];
    const int*   dN      = (const int*)d_in[5];
    float* out = (float*)d_out;
    float* x2s = (float*)d_ws;   // [N, ROW] accumulator, N read on device

    const int E = in_sizes[2];

    // 1) zero the node accumulator (size known only on device -> grid-stride kernel)
    zero_ws_kernel<<<1024, 256, 0, stream>>>(x2s, dN);

    // 2) scatter-add edges -> nodes
    long total = (long)E * ROW;
    int sblocks = (int)((total + 255) / 256);
    scatter_add_kernel<<<sblocks, 256, 0, stream>>>(x2, idxs, x2s, E);

    // 3) gather + per-(e,u) Wigner contraction
    dim3 grid((unsigned)((E + 64 * TEDGE - 1) / (64 * TEDGE)), MULV / UPB);
    contract_kernel<<<grid, 256, 0, stream>>>(x1, idxs, x2s, weights, w3j, out, E);
}